// Round 1
// baseline (255.598 us; speedup 1.0000x reference)
//
#include <hip/hip_runtime.h>
#include <hip/hip_bf16.h>
#include <math.h>

typedef __bf16 bf16;
typedef __bf16 bf16x8 __attribute__((ext_vector_type(8)));
typedef __bf16 bf16x4 __attribute__((ext_vector_type(4)));
typedef float  f32x4  __attribute__((ext_vector_type(4)));

#define NB 2
#define NL 2048
#define NC 256
#define NH 8
#define NDK 32
#define SCALE 0.17677669529663687f
#define NEGV  -4294967296.0f   // float32(-2^32+1) rounds to -2^32

// ---------------- fused QKV projection: [4096,256]@[256,256]+b -> bf16 ----------------
__global__ __launch_bounds__(256) void proj_kernel(
    const float* __restrict__ qx, const float* __restrict__ kx, const float* __restrict__ vx,
    const float* __restrict__ Wq, const float* __restrict__ bq,
    const float* __restrict__ Wk, const float* __restrict__ bk,
    const float* __restrict__ Wv, const float* __restrict__ bv,
    bf16* __restrict__ qo, bf16* __restrict__ ko, bf16* __restrict__ vto)
{
    const int mode = blockIdx.z;
    const float* X    = (mode == 0) ? qx : (mode == 1) ? kx : vx;
    const float* W    = (mode == 0) ? Wq : (mode == 1) ? Wk : Wv;
    const float* bias = (mode == 0) ? bq : (mode == 1) ? bk : bv;

    __shared__ float As[64][33];
    __shared__ float Bs[32][65];

    const int tid = threadIdx.x;
    const int tx = tid & 15, ty = tid >> 4;
    const int m0 = blockIdx.x * 64, n0 = blockIdx.y * 64;

    float acc[4][4] = {{0.f}};

    for (int k0 = 0; k0 < NC; k0 += 32) {
        const int ar = tid >> 2, ac = (tid & 3) << 3;
        const float4 a0 = *(const float4*)(X + (size_t)(m0 + ar) * NC + k0 + ac);
        const float4 a1 = *(const float4*)(X + (size_t)(m0 + ar) * NC + k0 + ac + 4);
        const int br = tid >> 3, bc = (tid & 7) << 3;
        const float4 b0 = *(const float4*)(W + (size_t)(k0 + br) * NC + n0 + bc);
        const float4 b1 = *(const float4*)(W + (size_t)(k0 + br) * NC + n0 + bc + 4);
        __syncthreads();
        As[ar][ac+0]=a0.x; As[ar][ac+1]=a0.y; As[ar][ac+2]=a0.z; As[ar][ac+3]=a0.w;
        As[ar][ac+4]=a1.x; As[ar][ac+5]=a1.y; As[ar][ac+6]=a1.z; As[ar][ac+7]=a1.w;
        Bs[br][bc+0]=b0.x; Bs[br][bc+1]=b0.y; Bs[br][bc+2]=b0.z; Bs[br][bc+3]=b0.w;
        Bs[br][bc+4]=b1.x; Bs[br][bc+5]=b1.y; Bs[br][bc+6]=b1.z; Bs[br][bc+7]=b1.w;
        __syncthreads();
        #pragma unroll
        for (int kk = 0; kk < 32; ++kk) {
            float av[4], bw[4];
            #pragma unroll
            for (int r = 0; r < 4; ++r) av[r] = As[ty*4+r][kk];
            #pragma unroll
            for (int c = 0; c < 4; ++c) bw[c] = Bs[kk][tx*4+c];
            #pragma unroll
            for (int r = 0; r < 4; ++r)
                #pragma unroll
                for (int c = 0; c < 4; ++c)
                    acc[r][c] = fmaf(av[r], bw[c], acc[r][c]);
        }
    }

    #pragma unroll
    for (int r = 0; r < 4; ++r) {
        const int row = m0 + ty*4 + r;
        const int bb_ = row >> 11, ll = row & (NL - 1);
        #pragma unroll
        for (int c = 0; c < 4; ++c) {
            const int col = n0 + tx*4 + c;
            const float v = acc[r][c] + bias[col];
            const int hh = col >> 5, d = col & 31;
            if (mode == 0)
                qo[(((size_t)bb_*NH + hh)*NL + ll)*NDK + d] = (bf16)v;
            else if (mode == 1)
                ko[(((size_t)bb_*NH + hh)*NL + ll)*NDK + d] = (bf16)v;
            else
                vto[(((size_t)bb_*NH + hh)*NDK + d)*NL + ll] = (bf16)v;
        }
    }
}

// ---------------- output GEMM: zbuf[4096,256]@WO[256,256]+b -> fp32 d_out ----------------
__global__ __launch_bounds__(256) void out_gemm_kernel(
    const float* __restrict__ Z, const float* __restrict__ W,
    const float* __restrict__ bias, float* __restrict__ out)
{
    __shared__ float As[64][33];
    __shared__ float Bs[32][65];

    const int tid = threadIdx.x;
    const int tx = tid & 15, ty = tid >> 4;
    const int m0 = blockIdx.x * 64, n0 = blockIdx.y * 64;

    float acc[4][4] = {{0.f}};

    for (int k0 = 0; k0 < NC; k0 += 32) {
        const int ar = tid >> 2, ac = (tid & 3) << 3;
        const float4 a0 = *(const float4*)(Z + (size_t)(m0 + ar) * NC + k0 + ac);
        const float4 a1 = *(const float4*)(Z + (size_t)(m0 + ar) * NC + k0 + ac + 4);
        const int br = tid >> 3, bc = (tid & 7) << 3;
        const float4 b0 = *(const float4*)(W + (size_t)(k0 + br) * NC + n0 + bc);
        const float4 b1 = *(const float4*)(W + (size_t)(k0 + br) * NC + n0 + bc + 4);
        __syncthreads();
        As[ar][ac+0]=a0.x; As[ar][ac+1]=a0.y; As[ar][ac+2]=a0.z; As[ar][ac+3]=a0.w;
        As[ar][ac+4]=a1.x; As[ar][ac+5]=a1.y; As[ar][ac+6]=a1.z; As[ar][ac+7]=a1.w;
        Bs[br][bc+0]=b0.x; Bs[br][bc+1]=b0.y; Bs[br][bc+2]=b0.z; Bs[br][bc+3]=b0.w;
        Bs[br][bc+4]=b1.x; Bs[br][bc+5]=b1.y; Bs[br][bc+6]=b1.z; Bs[br][bc+7]=b1.w;
        __syncthreads();
        #pragma unroll
        for (int kk = 0; kk < 32; ++kk) {
            float av[4], bw[4];
            #pragma unroll
            for (int r = 0; r < 4; ++r) av[r] = As[ty*4+r][kk];
            #pragma unroll
            for (int c = 0; c < 4; ++c) bw[c] = Bs[kk][tx*4+c];
            #pragma unroll
            for (int r = 0; r < 4; ++r)
                #pragma unroll
                for (int c = 0; c < 4; ++c)
                    acc[r][c] = fmaf(av[r], bw[c], acc[r][c]);
        }
    }

    #pragma unroll
    for (int r = 0; r < 4; ++r) {
        const int row = m0 + ty*4 + r;
        #pragma unroll
        for (int c = 0; c < 4; ++c) {
            const int col = n0 + tx*4 + c;
            out[(size_t)row * NC + col] = acc[r][c] + bias[col];
        }
    }
}

// ---------------- fused attention (flash-style, one pass) ----------------
// grid: (L/64, H, B), block 256 (4 waves x 16 rows each)
// Computes S^T = mfma(K, Q^T) so each lane holds 4 CONSECUTIVE j for one i:
// preScores/mask/scores traffic is float4/int4 vectorized.
__global__ __launch_bounds__(256) void attn_kernel(
    const bf16* __restrict__ q, const bf16* __restrict__ k, const bf16* __restrict__ vt,
    const float* __restrict__ preScores, const int* __restrict__ maskPAD,
    const float* __restrict__ embK, const float* __restrict__ embB,
    float* __restrict__ scores_out, float* __restrict__ zbuf)
{
    const int b  = blockIdx.z, h = blockIdx.y;
    const int i0 = blockIdx.x * 64;
    const int tid = threadIdx.x;
    const int lane = tid & 63, w = tid >> 6;
    const int l15 = lane & 15, g = lane >> 4;

    __shared__ __align__(16) bf16 Qs[64][40];
    __shared__ __align__(16) bf16 Ks[64][40];
    __shared__ __align__(16) bf16 Vts[32][72];
    __shared__ __align__(16) bf16 Ps[4][16][72];
    __shared__ float2 kbb[NL];

    // per-head rel-position LUT over distance d = |i-j|
    for (int d = tid; d < NL; d += 256) {
        const float fd = (float)d;
        float t = (d > 7) ? (7.0f + log2f(fd - 7.0f)) : fd;
        int idx = (int)t; idx = idx > 14 ? 14 : idx;
        kbb[d] = make_float2(embK[idx * NH + h], embB[idx * NH + h]);
    }

    const size_t bh = (size_t)b * NH + h;
    {
        const int r = tid >> 2, c = (tid & 3) << 3;
        const uint4 qv = *(const uint4*)(q + (bh * NL + i0 + r) * NDK + c);
        *(uint4*)&Qs[r][c] = qv;
    }
    __syncthreads();

    const bf16x8 bQ = *(const bf16x8*)&Qs[(w << 4) | l15][g * 8];

    f32x4 oF0 = {0.f, 0.f, 0.f, 0.f};
    f32x4 oF1 = {0.f, 0.f, 0.f, 0.f};
    float m_run = -INFINITY, l_run = 0.f;
    const f32x4 zf = {0.f, 0.f, 0.f, 0.f};

    const int i_row = i0 + (w << 4) + l15;             // this lane's softmax row
    const float* preRow  = preScores  + (bh * NL + i_row) * (size_t)NL;
    const int*   maskRow = maskPAD    + ((size_t)b * NL + i_row) * (size_t)NL;
    float*       scoreRow = scores_out + (bh * NL + i_row) * (size_t)NL;

    for (int j0 = 0; j0 < NL; j0 += 64) {
        // stage K (64x32) and V^T (32x64) tiles
        const int kr = tid >> 2, kc = (tid & 3) << 3;
        const uint4 kv = *(const uint4*)(k + (bh * NL + j0 + kr) * NDK + kc);
        const int vr = tid >> 3, vc = (tid & 7) << 3;
        const uint4 vv = *(const uint4*)(vt + (bh * NDK + vr) * NL + j0 + vc);
        __syncthreads();
        *(uint4*)&Ks[kr][kc]  = kv;
        *(uint4*)&Vts[vr][vc] = vv;
        __syncthreads();

        // S^T tiles: rows j, cols i
        f32x4 sf[4];
        #pragma unroll
        for (int tj = 0; tj < 4; ++tj) {
            const bf16x8 aK = *(const bf16x8*)&Ks[(tj << 4) | l15][g * 8];
            sf[tj] = __builtin_amdgcn_mfma_f32_16x16x32_bf16(aK, bQ, zf, 0, 0, 0);
        }

        float pv[4][4];
        float pmax = -INFINITY;
        #pragma unroll
        for (int tj = 0; tj < 4; ++tj) {
            const int jb = j0 + (tj << 4) + (g << 2);
            const float4 pre4 = *(const float4*)(preRow + jb);
            const int4   mk4  = *(const int4*)(maskRow + jb);
            float4 out4;
            #pragma unroll
            for (int r = 0; r < 4; ++r) {
                const int j = jb + r;
                int dd = i_row - j; dd = dd < 0 ? -dd : dd;
                const float2 kb2 = kbb[dd];
                float sv = sf[tj][r] * SCALE;
                sv = sv * kb2.x + kb2.y + (&pre4.x)[r];
                if ((&mk4.x)[r] == 0) sv = NEGV;
                (&out4.x)[r] = sv;
                pv[tj][r] = sv;
                pmax = fmaxf(pmax, sv);
            }
            *(float4*)(scoreRow + jb) = out4;
        }
        pmax = fmaxf(pmax, __shfl_xor(pmax, 16, 64));
        pmax = fmaxf(pmax, __shfl_xor(pmax, 32, 64));

        const float mn = fmaxf(m_run, pmax);
        const float sc = __expf(m_run - mn);
        m_run = mn;
        float rsum = 0.f;
        #pragma unroll
        for (int tj = 0; tj < 4; ++tj)
            #pragma unroll
            for (int r = 0; r < 4; ++r) {
                pv[tj][r] = __expf(pv[tj][r] - mn);
                rsum += pv[tj][r];
            }
        rsum += __shfl_xor(rsum, 16, 64);
        rsum += __shfl_xor(rsum, 32, 64);
        l_run = l_run * sc + rsum;

        // broadcast rescale factor to the lanes that own output rows
        #pragma unroll
        for (int r = 0; r < 4; ++r) {
            const float scr = __shfl(sc, 20 * g + r, 64);
            oF0[r] *= scr;
            oF1[r] *= scr;
        }

        // P -> LDS (row-major by i_local), 4 consecutive bf16 per write
        #pragma unroll
        for (int tj = 0; tj < 4; ++tj) {
            bf16x4 pk;
            pk[0] = (bf16)pv[tj][0];
            pk[1] = (bf16)pv[tj][1];
            pk[2] = (bf16)pv[tj][2];
            pk[3] = (bf16)pv[tj][3];
            *(bf16x4*)&Ps[w][l15][(tj << 4) | (g << 2)] = pk;
        }
        asm volatile("s_waitcnt lgkmcnt(0)" ::: "memory");

        // PV: Z += P * V
        #pragma unroll
        for (int cc = 0; cc < 2; ++cc) {
            const bf16x8 aP  = *(const bf16x8*)&Ps[w][l15][cc * 32 + g * 8];
            const bf16x8 bV0 = *(const bf16x8*)&Vts[l15][cc * 32 + g * 8];
            const bf16x8 bV1 = *(const bf16x8*)&Vts[16 + l15][cc * 32 + g * 8];
            oF0 = __builtin_amdgcn_mfma_f32_16x16x32_bf16(aP, bV0, oF0, 0, 0, 0);
            oF1 = __builtin_amdgcn_mfma_f32_16x16x32_bf16(aP, bV1, oF1, 0, 0, 0);
        }
    }

    const float linv = 1.0f / l_run;
    #pragma unroll
    for (int r = 0; r < 4; ++r) {
        const float li = __shfl(linv, 20 * g + r, 64);
        const int i = i0 + (w << 4) + (g << 2) + r;
        float* zr = zbuf + ((size_t)b * NL + i) * (size_t)(NH * NDK) + h * NDK;
        zr[l15]      = oF0[r] * li;
        zr[16 + l15] = oF1[r] * li;
    }
}

extern "C" void kernel_launch(void* const* d_in, const int* in_sizes, int n_in,
                              void* d_out, int out_size, void* d_ws, size_t ws_size,
                              hipStream_t stream) {
    (void)in_sizes; (void)n_in; (void)out_size; (void)ws_size;

    const float* qx        = (const float*)d_in[0];
    const float* kx        = (const float*)d_in[1];
    const float* vx        = (const float*)d_in[2];
    const float* preScores = (const float*)d_in[3];
    const int*   maskPAD   = (const int*)  d_in[4];
    const float* WQ_w      = (const float*)d_in[5];
    const float* WQ_b      = (const float*)d_in[6];
    const float* WK_w      = (const float*)d_in[7];
    const float* WK_b      = (const float*)d_in[8];
    const float* WV_w      = (const float*)d_in[9];
    const float* WV_b      = (const float*)d_in[10];
    const float* WO_w      = (const float*)d_in[11];
    const float* WO_b      = (const float*)d_in[12];
    const float* embK      = (const float*)d_in[13];
    const float* embB      = (const float*)d_in[14];

    char* ws = (char*)d_ws;
    bf16*  qb   = (bf16*)(ws);                    // 2 MB  [B,H,L,DK]
    bf16*  kb   = (bf16*)(ws + (2u << 20));       // 2 MB  [B,H,L,DK]
    bf16*  vtb  = (bf16*)(ws + (4u << 20));       // 2 MB  [B,H,DK,L]
    float* zbuf = (float*)(ws + (6u << 20));      // 4 MB  [B,L,H*DK]

    float* z_out      = (float*)d_out;                       // B*L*C
    float* scores_out = (float*)d_out + (size_t)NB * NL * NC; // B*H*L*L

    proj_kernel<<<dim3(64, 4, 3), 256, 0, stream>>>(
        qx, kx, vx, WQ_w, WQ_b, WK_w, WK_b, WV_w, WV_b, qb, kb, vtb);

    attn_kernel<<<dim3(NL / 64, NH, NB), 256, 0, stream>>>(
        qb, kb, vtb, preScores, maskPAD, embK, embB, scores_out, zbuf);

    out_gemm_kernel<<<dim3(64, 4), 256, 0, stream>>>(zbuf, WO_w, WO_b, z_out);
}

// Round 3
// 236.595 us; speedup vs baseline: 1.0803x; 1.0803x over previous
//
#include <hip/hip_runtime.h>
#include <hip/hip_bf16.h>
#include <math.h>

typedef __bf16 bf16;
typedef __bf16 bf16x8 __attribute__((ext_vector_type(8)));
typedef __bf16 bf16x4 __attribute__((ext_vector_type(4)));
typedef float  f32x4  __attribute__((ext_vector_type(4)));
typedef int    i32x4  __attribute__((ext_vector_type(4)));

#define NB 2
#define NL 2048
#define NC 256
#define NH 8
#define NDK 32
#define JSPLIT 4
#define JCHUNK (NL / JSPLIT)   // 512
#define JTILES (JCHUNK / 64)   // 8
#define SCALE 0.17677669529663687f
#define NEGV  -4294967296.0f   // float32(-2^32+1) rounds to -2^32

// ---------------- fused QKV projection: [4096,256]@[256,256]+b -> bf16 ----------------
__global__ __launch_bounds__(256) void proj_kernel(
    const float* __restrict__ qx, const float* __restrict__ kx, const float* __restrict__ vx,
    const float* __restrict__ Wq, const float* __restrict__ bq,
    const float* __restrict__ Wk, const float* __restrict__ bk,
    const float* __restrict__ Wv, const float* __restrict__ bv,
    bf16* __restrict__ qo, bf16* __restrict__ ko, bf16* __restrict__ vto)
{
    const int mode = blockIdx.z;
    const float* X    = (mode == 0) ? qx : (mode == 1) ? kx : vx;
    const float* W    = (mode == 0) ? Wq : (mode == 1) ? Wk : Wv;
    const float* bias = (mode == 0) ? bq : (mode == 1) ? bk : bv;

    __shared__ float As[64][33];
    __shared__ float Bs[32][65];

    const int tid = threadIdx.x;
    const int tx = tid & 15, ty = tid >> 4;
    const int m0 = blockIdx.x * 64, n0 = blockIdx.y * 64;

    float acc[4][4] = {{0.f}};

    for (int k0 = 0; k0 < NC; k0 += 32) {
        const int ar = tid >> 2, ac = (tid & 3) << 3;
        const float4 a0 = *(const float4*)(X + (size_t)(m0 + ar) * NC + k0 + ac);
        const float4 a1 = *(const float4*)(X + (size_t)(m0 + ar) * NC + k0 + ac + 4);
        const int br = tid >> 3, bc = (tid & 7) << 3;
        const float4 b0 = *(const float4*)(W + (size_t)(k0 + br) * NC + n0 + bc);
        const float4 b1 = *(const float4*)(W + (size_t)(k0 + br) * NC + n0 + bc + 4);
        __syncthreads();
        As[ar][ac+0]=a0.x; As[ar][ac+1]=a0.y; As[ar][ac+2]=a0.z; As[ar][ac+3]=a0.w;
        As[ar][ac+4]=a1.x; As[ar][ac+5]=a1.y; As[ar][ac+6]=a1.z; As[ar][ac+7]=a1.w;
        Bs[br][bc+0]=b0.x; Bs[br][bc+1]=b0.y; Bs[br][bc+2]=b0.z; Bs[br][bc+3]=b0.w;
        Bs[br][bc+4]=b1.x; Bs[br][bc+5]=b1.y; Bs[br][bc+6]=b1.z; Bs[br][bc+7]=b1.w;
        __syncthreads();
        #pragma unroll
        for (int kk = 0; kk < 32; ++kk) {
            float av[4], bw[4];
            #pragma unroll
            for (int r = 0; r < 4; ++r) av[r] = As[ty*4+r][kk];
            #pragma unroll
            for (int c = 0; c < 4; ++c) bw[c] = Bs[kk][tx*4+c];
            #pragma unroll
            for (int r = 0; r < 4; ++r)
                #pragma unroll
                for (int c = 0; c < 4; ++c)
                    acc[r][c] = fmaf(av[r], bw[c], acc[r][c]);
        }
    }

    #pragma unroll
    for (int r = 0; r < 4; ++r) {
        const int row = m0 + ty*4 + r;
        const int bb_ = row >> 11, ll = row & (NL - 1);
        #pragma unroll
        for (int c = 0; c < 4; ++c) {
            const int col = n0 + tx*4 + c;
            const float v = acc[r][c] + bias[col];
            const int hh = col >> 5, d = col & 31;
            if (mode == 0)
                qo[(((size_t)bb_*NH + hh)*NL + ll)*NDK + d] = (bf16)v;
            else if (mode == 1)
                ko[(((size_t)bb_*NH + hh)*NL + ll)*NDK + d] = (bf16)v;
            else
                vto[(((size_t)bb_*NH + hh)*NDK + d)*NL + ll] = (bf16)v;
        }
    }
}

// ---------------- output GEMM: zbuf[4096,256]@WO[256,256]+b -> fp32 ----------------
__global__ __launch_bounds__(256) void out_gemm_kernel(
    const float* __restrict__ Z, const float* __restrict__ W,
    const float* __restrict__ bias, float* __restrict__ out)
{
    __shared__ float As[32][33];
    __shared__ float Bs[32][65];

    const int tid = threadIdx.x;
    const int tx = tid & 15, ty = tid >> 4;
    const int m0 = blockIdx.x * 32, n0 = blockIdx.y * 64;

    float acc[2][4] = {{0.f}};

    for (int k0 = 0; k0 < NC; k0 += 32) {
        const int ar = tid >> 3, ac = (tid & 7) << 2;
        const float4 a0 = *(const float4*)(Z + (size_t)(m0 + ar) * NC + k0 + ac);
        const int br = tid >> 3, bc = (tid & 7) << 3;
        const float4 b0 = *(const float4*)(W + (size_t)(k0 + br) * NC + n0 + bc);
        const float4 b1 = *(const float4*)(W + (size_t)(k0 + br) * NC + n0 + bc + 4);
        __syncthreads();
        As[ar][ac+0]=a0.x; As[ar][ac+1]=a0.y; As[ar][ac+2]=a0.z; As[ar][ac+3]=a0.w;
        Bs[br][bc+0]=b0.x; Bs[br][bc+1]=b0.y; Bs[br][bc+2]=b0.z; Bs[br][bc+3]=b0.w;
        Bs[br][bc+4]=b1.x; Bs[br][bc+5]=b1.y; Bs[br][bc+6]=b1.z; Bs[br][bc+7]=b1.w;
        __syncthreads();
        #pragma unroll
        for (int kk = 0; kk < 32; ++kk) {
            float av[2], bw[4];
            av[0] = As[ty*2+0][kk];
            av[1] = As[ty*2+1][kk];
            #pragma unroll
            for (int c = 0; c < 4; ++c) bw[c] = Bs[kk][tx*4+c];
            #pragma unroll
            for (int r = 0; r < 2; ++r)
                #pragma unroll
                for (int c = 0; c < 4; ++c)
                    acc[r][c] = fmaf(av[r], bw[c], acc[r][c]);
        }
    }

    #pragma unroll
    for (int r = 0; r < 2; ++r) {
        const int row = m0 + ty*2 + r;
        #pragma unroll
        for (int c = 0; c < 4; ++c) {
            const int col = n0 + tx*4 + c;
            out[(size_t)row * NC + col] = acc[r][c] + bias[col];
        }
    }
}

// ---------------- fused attention, split-j flash ----------------
// grid: (32*H, JSPLIT, B), block 256 (4 waves x 16 rows each).
// blockIdx.x: h fastest so the 8 h-copies sharing a mask row dispatch adjacently.
__global__ __launch_bounds__(256, 4) void attn_kernel(
    const bf16* __restrict__ q, const bf16* __restrict__ k, const bf16* __restrict__ vt,
    const float* __restrict__ preScores, const int* __restrict__ maskPAD,
    const float* __restrict__ embK, const float* __restrict__ embB,
    float* __restrict__ scores_out, float* __restrict__ zp, float2* __restrict__ ml)
{
    const int h  = blockIdx.x & (NH - 1);
    const int i0 = (blockIdx.x >> 3) << 6;
    const int js = blockIdx.y;
    const int b  = blockIdx.z;
    const int tid = threadIdx.x;
    const int lane = tid & 63, w = tid >> 6;
    const int l15 = lane & 15, g = lane >> 4;

    __shared__ __align__(16) bf16 Ks[64][40];
    __shared__ __align__(16) bf16 Vts[32][72];
    __shared__ __align__(16) bf16 Ps[4][16][72];
    __shared__ float2 tab[16];

    if (tid < 15) tab[tid] = make_float2(embK[tid * NH + h], embB[tid * NH + h]);

    const size_t bh = (size_t)b * NH + h;
    const int i_row = i0 + (w << 4) + l15;
    const bf16x8 bQ = *(const bf16x8*)(q + (bh * NL + i_row) * NDK + g * 8);

    const int kr = tid >> 2, kc = (tid & 3) << 3;
    const int vr = tid >> 3, vc = (tid & 7) << 3;
    const bf16* kbase = k  + (bh * NL + kr) * NDK + kc;    // + j0*NDK
    const bf16* vbase = vt + (bh * NDK + vr) * NL + vc;    // + j0

    const float* preRow   = preScores  + (bh * NL + i_row) * (size_t)NL;
    const int*   maskRow  = maskPAD    + ((size_t)b * NL + i_row) * (size_t)NL;
    float*       scoreRow = scores_out + (bh * NL + i_row) * (size_t)NL;

    f32x4 oF0 = {0.f, 0.f, 0.f, 0.f};
    f32x4 oF1 = {0.f, 0.f, 0.f, 0.f};
    float m_run = -INFINITY, l_run = 0.f;
    const f32x4 zf = {0.f, 0.f, 0.f, 0.f};

    const int jc0 = js * JCHUNK;

    // prologue: prime tile 0
    uint4 kv_c = *(const uint4*)(kbase + (size_t)jc0 * NDK);
    uint4 vv_c = *(const uint4*)(vbase + jc0);
    f32x4 pre_c[4]; i32x4 mk_c[4];
    #pragma unroll
    for (int tj = 0; tj < 4; ++tj) {
        const int jb = jc0 + (tj << 4) + (g << 2);
        pre_c[tj] = __builtin_nontemporal_load((const f32x4*)(preRow + jb));
        mk_c[tj]  = *(const i32x4*)(maskRow + jb);
    }

    #pragma unroll
    for (int jt = 0; jt < JTILES; ++jt) {
        const int j0 = jc0 + jt * 64;

        // (a) previous tile's LDS reads complete in every wave
        asm volatile("s_waitcnt lgkmcnt(0)" ::: "memory");
        __builtin_amdgcn_s_barrier();
        *(uint4*)&Ks[kr][kc]  = kv_c;     // compiler inserts vmcnt wait for kv_c
        *(uint4*)&Vts[vr][vc] = vv_c;
        // (b) staging visible to all waves (NO vmcnt drain: prefetches stay in flight)
        asm volatile("s_waitcnt lgkmcnt(0)" ::: "memory");
        __builtin_amdgcn_s_barrier();

        // S^T = mfma(K, Q): lane (l15,g) -> i = l15-row, j = tj*16 + g*4 + r
        f32x4 sf[4];
        #pragma unroll
        for (int tj = 0; tj < 4; ++tj) {
            const bf16x8 aK = *(const bf16x8*)&Ks[(tj << 4) | l15][g * 8];
            sf[tj] = __builtin_amdgcn_mfma_f32_16x16x32_bf16(aK, bQ, zf, 0, 0, 0);
        }

        // prefetch next K/V (needed earliest, next staging)
        uint4 kv_n, vv_n;
        if (jt + 1 < JTILES) {
            kv_n = *(const uint4*)(kbase + (size_t)(j0 + 64) * NDK);
            vv_n = *(const uint4*)(vbase + (j0 + 64));
        }

        // scores = S*kb + bb + pre, masked; stream out
        float pmax = -INFINITY;
        #pragma unroll
        for (int tj = 0; tj < 4; ++tj) {
            const int jb = j0 + (tj << 4) + (g << 2);
            f32x4 out4;
            #pragma unroll
            for (int r = 0; r < 4; ++r) {
                const int j = jb + r;
                int dd = i_row - j; dd = dd < 0 ? -dd : dd;
                int idx = dd;
                if (dd > 7) {
                    idx = 38 - __clz(dd - 7);   // 7 + floor(log2(dd-7)), exact
                    idx = idx > 14 ? 14 : idx;
                }
                const float2 kb2 = tab[idx];
                float sv = sf[tj][r] * SCALE;
                sv = sv * kb2.x + kb2.y + pre_c[tj][r];
                if (mk_c[tj][r] == 0) sv = NEGV;
                out4[r] = sv;
                sf[tj][r] = sv;
                pmax = fmaxf(pmax, sv);
            }
            __builtin_nontemporal_store(out4, (f32x4*)(scoreRow + jb));
        }

        // prefetch next pre/mask (consumed one full tile later)
        f32x4 pre_n[4]; i32x4 mk_n[4];
        if (jt + 1 < JTILES) {
            #pragma unroll
            for (int tj = 0; tj < 4; ++tj) {
                const int jb = j0 + 64 + (tj << 4) + (g << 2);
                pre_n[tj] = __builtin_nontemporal_load((const f32x4*)(preRow + jb));
                mk_n[tj]  = *(const i32x4*)(maskRow + jb);
            }
        }

        pmax = fmaxf(pmax, __shfl_xor(pmax, 16, 64));
        pmax = fmaxf(pmax, __shfl_xor(pmax, 32, 64));

        const float mn = fmaxf(m_run, pmax);
        const float sc = __expf(m_run - mn);
        m_run = mn;
        float rsum = 0.f;
        #pragma unroll
        for (int tj = 0; tj < 4; ++tj)
            #pragma unroll
            for (int r = 0; r < 4; ++r) {
                const float e = __expf(sf[tj][r] - mn);
                sf[tj][r] = e;
                rsum += e;
            }
        rsum += __shfl_xor(rsum, 16, 64);
        rsum += __shfl_xor(rsum, 32, 64);
        l_run = l_run * sc + rsum;

        // rescale accumulators (rows g*4+r live in lane 16g + 4g + r)
        #pragma unroll
        for (int r = 0; r < 4; ++r) {
            const float scr = __shfl(sc, 20 * g + r, 64);
            oF0[r] *= scr;
            oF1[r] *= scr;
        }

        // P -> LDS (per-wave buffer)
        #pragma unroll
        for (int tj = 0; tj < 4; ++tj) {
            bf16x4 pk;
            pk[0] = (bf16)sf[tj][0];
            pk[1] = (bf16)sf[tj][1];
            pk[2] = (bf16)sf[tj][2];
            pk[3] = (bf16)sf[tj][3];
            *(bf16x4*)&Ps[w][l15][(tj << 4) | (g << 2)] = pk;
        }
        asm volatile("s_waitcnt lgkmcnt(0)" ::: "memory");

        // PV
        #pragma unroll
        for (int cc = 0; cc < 2; ++cc) {
            const bf16x8 aP  = *(const bf16x8*)&Ps[w][l15][cc * 32 + g * 8];
            const bf16x8 bV0 = *(const bf16x8*)&Vts[l15][cc * 32 + g * 8];
            const bf16x8 bV1 = *(const bf16x8*)&Vts[16 + l15][cc * 32 + g * 8];
            oF0 = __builtin_amdgcn_mfma_f32_16x16x32_bf16(aP, bV0, oF0, 0, 0, 0);
            oF1 = __builtin_amdgcn_mfma_f32_16x16x32_bf16(aP, bV1, oF1, 0, 0, 0);
        }

        if (jt + 1 < JTILES) {
            kv_c = kv_n; vv_c = vv_n;
            #pragma unroll
            for (int t = 0; t < 4; ++t) { pre_c[t] = pre_n[t]; mk_c[t] = mk_n[t]; }
        }
    }

    // write partials (unnormalized)
    #pragma unroll
    for (int r = 0; r < 4; ++r) {
        const int i = i0 + (w << 4) + (g << 2) + r;
        float* zr = zp + ((bh * JSPLIT + js) * (size_t)NL + i) * NDK;
        zr[l15]      = oF0[r];
        zr[16 + l15] = oF1[r];
    }
    if (g == 0)
        ml[(bh * JSPLIT + js) * (size_t)NL + i_row] = make_float2(m_run, l_run);
}

// ---------------- combine partials -> zbuf ----------------
__global__ __launch_bounds__(256) void combine_kernel(
    const float* __restrict__ zp, const float2* __restrict__ ml, float* __restrict__ zbuf)
{
    const int gid = blockIdx.x * 256 + threadIdx.x;
    const int d   = gid & (NDK - 1);
    const int row = gid >> 5;              // bh*NL + i
    const int i   = row & (NL - 1);
    const int bh  = row >> 11;
    const int h   = bh & (NH - 1), b = bh >> 3;

    float m[JSPLIT], l[JSPLIT];
    float M = -INFINITY;
    #pragma unroll
    for (int js = 0; js < JSPLIT; ++js) {
        const float2 t = ml[((size_t)bh * JSPLIT + js) * NL + i];
        m[js] = t.x; l[js] = t.y;
        M = fmaxf(M, t.x);
    }
    float L = 0.f, zs = 0.f;
    #pragma unroll
    for (int js = 0; js < JSPLIT; ++js) {
        const float e = __expf(m[js] - M);
        L += l[js] * e;
        zs = fmaf(zp[(((size_t)bh * JSPLIT + js) * NL + i) * NDK + d], e, zs);
    }
    zbuf[((size_t)b * NL + i) * NC + h * NDK + d] = zs / L;
}

extern "C" void kernel_launch(void* const* d_in, const int* in_sizes, int n_in,
                              void* d_out, int out_size, void* d_ws, size_t ws_size,
                              hipStream_t stream) {
    (void)in_sizes; (void)n_in; (void)out_size; (void)ws_size;

    const float* qx        = (const float*)d_in[0];
    const float* kx        = (const float*)d_in[1];
    const float* vx        = (const float*)d_in[2];
    const float* preScores = (const float*)d_in[3];
    const int*   maskPAD   = (const int*)  d_in[4];
    const float* WQ_w      = (const float*)d_in[5];
    const float* WQ_b      = (const float*)d_in[6];
    const float* WK_w      = (const float*)d_in[7];
    const float* WK_b      = (const float*)d_in[8];
    const float* WV_w      = (const float*)d_in[9];
    const float* WV_b      = (const float*)d_in[10];
    const float* WO_w      = (const float*)d_in[11];
    const float* WO_b      = (const float*)d_in[12];
    const float* embK      = (const float*)d_in[13];
    const float* embB      = (const float*)d_in[14];

    char* ws = (char*)d_ws;
    bf16*   qb   = (bf16*)(ws);                    // 2 MB  [B,H,L,DK]
    bf16*   kb   = (bf16*)(ws + (2u << 20));       // 2 MB  [B,H,L,DK]
    bf16*   vtb  = (bf16*)(ws + (4u << 20));       // 2 MB  [B,H,DK,L]
    float*  zbuf = (float*)(ws + (6u << 20));      // 4 MB  [B,L,H*DK]
    float*  zp   = (float*)(ws + (10u << 20));     // 16 MB [B,H,JSPLIT,L,DK]
    float2* mlb  = (float2*)(ws + (26u << 20));    // 1 MB  [B,H,JSPLIT,L]

    float* z_out      = (float*)d_out;                        // B*L*C
    float* scores_out = (float*)d_out + (size_t)NB * NL * NC; // B*H*L*L

    proj_kernel<<<dim3(64, 4, 3), 256, 0, stream>>>(
        qx, kx, vx, WQ_w, WQ_b, WK_w, WK_b, WV_w, WV_b, qb, kb, vtb);

    attn_kernel<<<dim3((NL / 64) * NH, JSPLIT, NB), 256, 0, stream>>>(
        qb, kb, vtb, preScores, maskPAD, embK, embB, scores_out, zp, mlb);

    combine_kernel<<<dim3((NB * NH * NL * NDK) / 256), 256, 0, stream>>>(zp, mlb, zbuf);

    out_gemm_kernel<<<dim3(NB * NL / 32, 4), 256, 0, stream>>>(zbuf, WO_w, WO_b, z_out);
}